// Round 1
// 416.851 us; speedup vs baseline: 1.0258x; 1.0258x over previous
//
#include <hip/hip_runtime.h>

// LSTM B=256, T=1024, I=64, H=128. One block/batch row (256 blocks = 256 CUs).
// R9 = R8 + three latency cuts aimed at the per-step lockstep bubble
// (MFMA issue floor ~640 cyc/step; R8 measured ~1000 cyc/step):
//  1. Gate order: (f,g) chains first, (i,o) second with i leading. The post-
//     last-MFMA tail shrinks from sigma(f),sigma(o),c,tanh(c),h (~80cy) to
//     sigma(o)*tc (~30cy) -- the c/tanh(c) chain overlaps the o-chain MFMAs,
//     sigma(f)/f*c/tanh(g) overlap the (i,o) issue.
//  2. exp2 folding: gate weights+biases pre-scaled by -log2e (i,f,o) and
//     -2*log2e (g) so every activation is rcp(1+exp2(q)) / (1-e)*rcp(1+e)
//     with a bare v_exp_f32 -- no per-activation scale mul on the tail.
//  3. Next-chunk xw-GEMM spread: its 8 MFMA + 8 pk16 + 4 x-loads go one-per-
//     step into the post-barrier ds_read shadow (XTRA slot), removing the
//     chunk-top serial lump and filling the read-latency bubble.
// launch_bounds relaxed to (512,1): +24 VGPR for nxw/nax would spill at the
// (512,2) 128-cap; one 8-wave block/CU still resident at <=256 VGPR.

typedef _Float16 half8  __attribute__((ext_vector_type(8)));
typedef _Float16 half2t __attribute__((ext_vector_type(2)));
typedef float  floatx4  __attribute__((ext_vector_type(4)));

constexpr int Tt = 1024;
constexpr int Ii = 64;
constexpr int Hh = 128;
constexpr int CH = 16;          // timesteps per x chunk-GEMM
constexpr int NCH = Tt / CH;    // 64 chunks

__device__ __forceinline__ float fast_rcp(float x) { return __builtin_amdgcn_rcpf(x); }
__device__ __forceinline__ float exp2_(float x)    { return __builtin_amdgcn_exp2f(x); }
__device__ __forceinline__ half2t pk16(float a, float b) {
    return __builtin_bit_cast(half2t, __builtin_amdgcn_cvt_pkrtz(a, b));
}
#define MFMA16(A, B, C) __builtin_amdgcn_mfma_f32_16x16x32_f16((A), (B), (C), 0, 0, 0)
union H8U { half8 v; half2t p[4]; };

__device__ __forceinline__ half8 cvt8(float4 a, float4 b) {
    H8U u;
    u.p[0] = pk16(a.x, a.y); u.p[1] = pk16(a.z, a.w);
    u.p[2] = pk16(b.x, b.y); u.p[3] = pk16(b.z, b.w);
    return u.v;
}
__device__ __forceinline__ floatx4 splat4(float a) { floatx4 r = {a, a, a, a}; return r; }

__global__ __launch_bounds__(512, 1) void lstm_mfma5(
    const float* __restrict__ data,   // [B, T, I]
    const float* __restrict__ W_ih,   // [4H, I]
    const float* __restrict__ W_hh,   // [4H, H]
    const float* __restrict__ b_ih,   // [4H]
    const float* __restrict__ b_hh,   // [4H]
    float* __restrict__ out)          // [B, T, H] f32
{
    const int b   = blockIdx.x;
    const int t   = threadIdx.x;
    const int w   = t >> 6;    // wave 0..7
    const int l   = t & 63;    // lane
    const int col = l & 15;    // N-col == hidden unit offset within wave's 16
    const int kg  = l >> 4;    // k-group / C-row group

    // ---- weights static in VGPRs, pre-scaled by the exp2 gate constants ----
    // gates 0(i),1(f),3(o): sigma(x)=rcp(1+exp2(-log2e*x))
    // gate 2(g):            tanh(x) via e=exp2(-2log2e*x), (1-e)*rcp(1+e)
    half8 bfh[4][4];   // Whh: 4 gates x 4 K-slices (K=128)
    half8 bfx[4][2];   // Wih: 4 gates x 2 K-slices (K=64)
    float bs[4];       // scaled bias (chunk-GEMM C-init)
#pragma unroll
    for (int g = 0; g < 4; ++g) {
        const float sc = (g == 2) ? -2.8853900817779268f : -1.4426950408889634f;
        const int row = 128 * g + 16 * w + col;
        bs[g] = sc * (b_ih[row] + b_hh[row]);
        const float* wh = W_hh + (size_t)row * Hh;
        const float* wi = W_ih + (size_t)row * Ii;
#pragma unroll
        for (int s = 0; s < 4; ++s) {
            const float* src = wh + 32 * s + 8 * kg;
            const float4 f0 = ((const float4*)src)[0];
            const float4 f1 = ((const float4*)src)[1];
            H8U u;
            u.p[0] = pk16(sc * f0.x, sc * f0.y); u.p[1] = pk16(sc * f0.z, sc * f0.w);
            u.p[2] = pk16(sc * f1.x, sc * f1.y); u.p[3] = pk16(sc * f1.z, sc * f1.w);
            bfh[g][s] = u.v;
        }
#pragma unroll
        for (int s = 0; s < 2; ++s) {
            const float* src = wi + 32 * s + 8 * kg;
            const float4 f0 = ((const float4*)src)[0];
            const float4 f1 = ((const float4*)src)[1];
            H8U u;
            u.p[0] = pk16(sc * f0.x, sc * f0.y); u.p[1] = pk16(sc * f0.z, sc * f0.w);
            u.p[2] = pk16(sc * f1.x, sc * f1.y); u.p[3] = pk16(sc * f1.z, sc * f1.w);
            bfx[g][s] = u.v;
        }
    }

    __shared__ __align__(16) _Float16 hb[2][Hh];   // h double buffer (2x256B)

    const float* xp  = data + (size_t)b * Tt * Ii;
    float*       opr = out  + (size_t)b * Tt * Hh + 16 * w + col;

    if (t < Hh) hb[0][t] = (_Float16)0.0f;        // h0 = 0

    // x chunk staging: lane reads x[t0 + (l&15)][32*s2 + 8*kg + j], j=0..7
    const float* xbase = xp + (size_t)(l & 15) * Ii + 8 * kg;
    float4 xf0 = *(const float4*)(xbase);
    float4 xf1 = *(const float4*)(xbase + 4);
    float4 xf2 = *(const float4*)(xbase + 32);
    float4 xf3 = *(const float4*)(xbase + 36);

    // ---- prologue: chunk-0 xw, chunk-1 x loads in flight under it ----
    half8 ax0 = cvt8(xf0, xf1);
    half8 ax1 = cvt8(xf2, xf3);
    xf0 = *(const float4*)(xbase + CH * Ii);
    xf1 = *(const float4*)(xbase + CH * Ii + 4);
    xf2 = *(const float4*)(xbase + CH * Ii + 32);
    xf3 = *(const float4*)(xbase + CH * Ii + 36);
    floatx4 xw0 = MFMA16(ax0, bfx[0][0], splat4(bs[0]));
    floatx4 xw1 = MFMA16(ax0, bfx[1][0], splat4(bs[1]));
    floatx4 xw2 = MFMA16(ax0, bfx[2][0], splat4(bs[2]));
    floatx4 xw3 = MFMA16(ax0, bfx[3][0], splat4(bs[3]));
    xw0 = MFMA16(ax1, bfx[0][1], xw0);
    xw1 = MFMA16(ax1, bfx[1][1], xw1);
    xw2 = MFMA16(ax1, bfx[2][1], xw2);
    xw3 = MFMA16(ax1, bfx[3][1], xw3);

    half8 nax0, nax1;                 // next chunk's A fragments
    floatx4 nxw0, nxw1, nxw2, nxw3;   // next chunk's xW+bias accumulators

    float c = 0.0f;
    __syncthreads();   // h0 visible (one full drain, outside the loop)

#pragma unroll 1
    for (int n = 0; n < NCH; ++n) {
        const float* xb2 = xbase + (size_t)((n + 2 < NCH) ? n + 2 : NCH - 1) * CH * Ii;

        // step s = 16n + 4P + R; h buffer parity = R&1 (16n+4P even).
        // (f,g) chains complete first; i leads o so the c/tanh chain overlaps
        // the o-chain; tail after last MFMA is just sigma(o)*tc + pack/write.
#define STEP(P, R, CUR, XTRA)                                                 \
        {                                                                     \
            const _Float16* hbase = &hb[CUR][8 * kg];                         \
            const half8 ah0 = *(const half8*)(hbase);                         \
            const half8 ah1 = *(const half8*)(hbase + 32);                    \
            const half8 ah2 = *(const half8*)(hbase + 64);                    \
            const half8 ah3 = *(const half8*)(hbase + 96);                    \
            XTRA;                                                             \
            __builtin_amdgcn_s_setprio(1);                                    \
            floatx4 qf = MFMA16(ah0, bfh[1][0], xw1);   /* f */               \
            floatx4 qg = MFMA16(ah0, bfh[2][0], xw2);   /* g */               \
            qf = MFMA16(ah1, bfh[1][1], qf);                                  \
            qg = MFMA16(ah1, bfh[2][1], qg);                                  \
            qf = MFMA16(ah2, bfh[1][2], qf);                                  \
            qg = MFMA16(ah2, bfh[2][2], qg);                                  \
            qf = MFMA16(ah3, bfh[1][3], qf);                                  \
            qg = MFMA16(ah3, bfh[2][3], qg);                                  \
            floatx4 qi = MFMA16(ah0, bfh[0][0], xw0);   /* i */               \
            floatx4 qo = MFMA16(ah0, bfh[3][0], xw3);   /* o */               \
            const float fg = fast_rcp(1.0f + exp2_(qf[R]));                   \
            const float eg = exp2_(qg[R]);                                    \
            qi = MFMA16(ah1, bfh[0][1], qi);                                  \
            qo = MFMA16(ah1, bfh[3][1], qo);                                  \
            const float fc = fg * c;                                          \
            const float gv = (1.0f - eg) * fast_rcp(1.0f + eg);               \
            qi = MFMA16(ah2, bfh[0][2], qi);                                  \
            qo = MFMA16(ah2, bfh[3][2], qo);                                  \
            qi = MFMA16(ah3, bfh[0][3], qi);                                  \
            qo = MFMA16(ah3, bfh[3][3], qo);                                  \
            __builtin_amdgcn_s_setprio(0);                                    \
            const float ig = fast_rcp(1.0f + exp2_(qi[R]));                   \
            c = fmaf(ig, gv, fc);                                             \
            const float ec = exp2_(-2.8853900817779268f * c);                 \
            const float tc = (1.0f - ec) * fast_rcp(1.0f + ec);               \
            const float og = fast_rcp(1.0f + exp2_(qo[R]));                   \
            const float h  = og * tc;                                         \
            if (kg == (P)) {                                                  \
                hb[(CUR) ^ 1][16 * w + col] = (_Float16)h;                    \
                *opr = h;                                                     \
            }                                                                 \
            opr += Hh;                                                        \
            asm volatile("s_waitcnt lgkmcnt(0)\n\ts_barrier" ::: "memory");   \
        }

        // phase P handles steps 4P..4P+3; c lineage hops lane-groups:
        // rotate c from group P-1 (or prev chunk's group 3) into group P.
#define PHASE(P, X0, X1, X2, X3)                                              \
        c = __shfl(c, (l + 48) & 63);                                         \
        STEP(P, 0, 0, X0) STEP(P, 1, 1, X1) STEP(P, 2, 0, X2) STEP(P, 3, 1, X3)

        PHASE(0,
              nax0 = cvt8(xf0, xf1),
              nax1 = cvt8(xf2, xf3),
              nxw0 = MFMA16(nax0, bfx[0][0], splat4(bs[0])),
              nxw1 = MFMA16(nax0, bfx[1][0], splat4(bs[1])))
        PHASE(1,
              nxw2 = MFMA16(nax0, bfx[2][0], splat4(bs[2])),
              nxw3 = MFMA16(nax0, bfx[3][0], splat4(bs[3])),
              nxw0 = MFMA16(nax1, bfx[0][1], nxw0),
              nxw1 = MFMA16(nax1, bfx[1][1], nxw1))
        PHASE(2,
              nxw2 = MFMA16(nax1, bfx[2][1], nxw2),
              nxw3 = MFMA16(nax1, bfx[3][1], nxw3),
              xf0 = *(const float4*)(xb2),
              xf1 = *(const float4*)(xb2 + 4))
        PHASE(3,
              xf2 = *(const float4*)(xb2 + 32),
              xf3 = *(const float4*)(xb2 + 36),
              (void)0,
              (void)0)
#undef PHASE
#undef STEP

        xw0 = nxw0; xw1 = nxw1; xw2 = nxw2; xw3 = nxw3;
    }
}

extern "C" void kernel_launch(void* const* d_in, const int* in_sizes, int n_in,
                              void* d_out, int out_size, void* d_ws, size_t ws_size,
                              hipStream_t stream) {
    const float* data = (const float*)d_in[0];
    const float* W_ih = (const float*)d_in[1];
    const float* W_hh = (const float*)d_in[2];
    const float* b_ih = (const float*)d_in[3];
    const float* b_hh = (const float*)d_in[4];
    float* out = (float*)d_out;

    hipLaunchKernelGGL(lstm_mfma5, dim3(256), dim3(512), 0, stream,
                       data, W_ih, W_hh, b_ih, b_hh, out);
}

// Round 2
// 416.840 us; speedup vs baseline: 1.0258x; 1.0000x over previous
//
#include <hip/hip_runtime.h>

// LSTM B=256, T=1024, I=64, H=128. One block/batch row (256 blocks = 256 CUs).
// R10 = R9 + MFMA dependency-underfeed fixes:
//  1. 4-chain interleave: f,g,i chains issued round-robin with o trailing one
//     K-slice. 3-4 independent accumulator chains per wave (7-8 per SIMD with
//     2 waves) vs R9's 2 -- covers ~32cyc dependent-MFMA latency at ~4cyc
//     issue. o still completes last so the exposed tail stays sigma(o)*tc.
//  2. c-rotation __shfl moved AFTER the step's ds_read issues (DS returns are
//     in-order per wave; shfl-before-reads delayed ah0 by an LDS round trip
//     every 4th step).
//  3. f/g/i activations + c-chain slotted between the trailing o-MFMAs.
// Floor: ~128 h-MFMA/CU/step x ~4 cyc ~ 512 cyc; R9 measured ~977 (MfmaUtil
// 50% => ~450 cyc/step pipe-idle, read-latency + chain-underfeed).

typedef _Float16 half8  __attribute__((ext_vector_type(8)));
typedef _Float16 half2t __attribute__((ext_vector_type(2)));
typedef float  floatx4  __attribute__((ext_vector_type(4)));

constexpr int Tt = 1024;
constexpr int Ii = 64;
constexpr int Hh = 128;
constexpr int CH = 16;          // timesteps per x chunk-GEMM
constexpr int NCH = Tt / CH;    // 64 chunks

__device__ __forceinline__ float fast_rcp(float x) { return __builtin_amdgcn_rcpf(x); }
__device__ __forceinline__ float exp2_(float x)    { return __builtin_amdgcn_exp2f(x); }
__device__ __forceinline__ half2t pk16(float a, float b) {
    return __builtin_bit_cast(half2t, __builtin_amdgcn_cvt_pkrtz(a, b));
}
#define MFMA16(A, B, C) __builtin_amdgcn_mfma_f32_16x16x32_f16((A), (B), (C), 0, 0, 0)
union H8U { half8 v; half2t p[4]; };

__device__ __forceinline__ half8 cvt8(float4 a, float4 b) {
    H8U u;
    u.p[0] = pk16(a.x, a.y); u.p[1] = pk16(a.z, a.w);
    u.p[2] = pk16(b.x, b.y); u.p[3] = pk16(b.z, b.w);
    return u.v;
}
__device__ __forceinline__ floatx4 splat4(float a) { floatx4 r = {a, a, a, a}; return r; }

__global__ __launch_bounds__(512, 1) void lstm_mfma6(
    const float* __restrict__ data,   // [B, T, I]
    const float* __restrict__ W_ih,   // [4H, I]
    const float* __restrict__ W_hh,   // [4H, H]
    const float* __restrict__ b_ih,   // [4H]
    const float* __restrict__ b_hh,   // [4H]
    float* __restrict__ out)          // [B, T, H] f32
{
    const int b   = blockIdx.x;
    const int t   = threadIdx.x;
    const int w   = t >> 6;    // wave 0..7
    const int l   = t & 63;    // lane
    const int col = l & 15;    // N-col == hidden unit offset within wave's 16
    const int kg  = l >> 4;    // k-group / C-row group

    // ---- weights static in VGPRs, pre-scaled by the exp2 gate constants ----
    // gates 0(i),1(f),3(o): sigma(x)=rcp(1+exp2(-log2e*x))
    // gate 2(g):            tanh(x) via e=exp2(-2log2e*x), (1-e)*rcp(1+e)
    half8 bfh[4][4];   // Whh: 4 gates x 4 K-slices (K=128)
    half8 bfx[4][2];   // Wih: 4 gates x 2 K-slices (K=64)
    float bs[4];       // scaled bias (chunk-GEMM C-init)
#pragma unroll
    for (int g = 0; g < 4; ++g) {
        const float sc = (g == 2) ? -2.8853900817779268f : -1.4426950408889634f;
        const int row = 128 * g + 16 * w + col;
        bs[g] = sc * (b_ih[row] + b_hh[row]);
        const float* wh = W_hh + (size_t)row * Hh;
        const float* wi = W_ih + (size_t)row * Ii;
#pragma unroll
        for (int s = 0; s < 4; ++s) {
            const float* src = wh + 32 * s + 8 * kg;
            const float4 f0 = ((const float4*)src)[0];
            const float4 f1 = ((const float4*)src)[1];
            H8U u;
            u.p[0] = pk16(sc * f0.x, sc * f0.y); u.p[1] = pk16(sc * f0.z, sc * f0.w);
            u.p[2] = pk16(sc * f1.x, sc * f1.y); u.p[3] = pk16(sc * f1.z, sc * f1.w);
            bfh[g][s] = u.v;
        }
#pragma unroll
        for (int s = 0; s < 2; ++s) {
            const float* src = wi + 32 * s + 8 * kg;
            const float4 f0 = ((const float4*)src)[0];
            const float4 f1 = ((const float4*)src)[1];
            H8U u;
            u.p[0] = pk16(sc * f0.x, sc * f0.y); u.p[1] = pk16(sc * f0.z, sc * f0.w);
            u.p[2] = pk16(sc * f1.x, sc * f1.y); u.p[3] = pk16(sc * f1.z, sc * f1.w);
            bfx[g][s] = u.v;
        }
    }

    __shared__ __align__(16) _Float16 hb[2][Hh];   // h double buffer (2x256B)

    const float* xp  = data + (size_t)b * Tt * Ii;
    float*       opr = out  + (size_t)b * Tt * Hh + 16 * w + col;

    if (t < Hh) hb[0][t] = (_Float16)0.0f;        // h0 = 0

    // x chunk staging: lane reads x[t0 + (l&15)][32*s2 + 8*kg + j], j=0..7
    const float* xbase = xp + (size_t)(l & 15) * Ii + 8 * kg;
    float4 xf0 = *(const float4*)(xbase);
    float4 xf1 = *(const float4*)(xbase + 4);
    float4 xf2 = *(const float4*)(xbase + 32);
    float4 xf3 = *(const float4*)(xbase + 36);

    // ---- prologue: chunk-0 xw, chunk-1 x loads in flight under it ----
    half8 ax0 = cvt8(xf0, xf1);
    half8 ax1 = cvt8(xf2, xf3);
    xf0 = *(const float4*)(xbase + CH * Ii);
    xf1 = *(const float4*)(xbase + CH * Ii + 4);
    xf2 = *(const float4*)(xbase + CH * Ii + 32);
    xf3 = *(const float4*)(xbase + CH * Ii + 36);
    floatx4 xw0 = MFMA16(ax0, bfx[0][0], splat4(bs[0]));
    floatx4 xw1 = MFMA16(ax0, bfx[1][0], splat4(bs[1]));
    floatx4 xw2 = MFMA16(ax0, bfx[2][0], splat4(bs[2]));
    floatx4 xw3 = MFMA16(ax0, bfx[3][0], splat4(bs[3]));
    xw0 = MFMA16(ax1, bfx[0][1], xw0);
    xw1 = MFMA16(ax1, bfx[1][1], xw1);
    xw2 = MFMA16(ax1, bfx[2][1], xw2);
    xw3 = MFMA16(ax1, bfx[3][1], xw3);

    half8 nax0, nax1;                 // next chunk's A fragments
    floatx4 nxw0, nxw1, nxw2, nxw3;   // next chunk's xW+bias accumulators

    float c = 0.0f;
    __syncthreads();   // h0 visible (one full drain, outside the loop)

#pragma unroll 1
    for (int n = 0; n < NCH; ++n) {
        const float* xb2 = xbase + (size_t)((n + 2 < NCH) ? n + 2 : NCH - 1) * CH * Ii;

        // step s = 16n + 4P + R; h buffer parity = R&1 (16n+4P even).
        // f,g,i chains interleaved (3 live chains); o trails one K-slice so
        // the exposed post-MFMA tail is just sigma(o)*tc + pack/write.
#define STEP(P, R, CUR, XTRA)                                                 \
        {                                                                     \
            const _Float16* hbase = &hb[CUR][8 * kg];                         \
            const half8 ah0 = *(const half8*)(hbase);                         \
            const half8 ah1 = *(const half8*)(hbase + 32);                    \
            const half8 ah2 = *(const half8*)(hbase + 64);                    \
            const half8 ah3 = *(const half8*)(hbase + 96);                    \
            XTRA;                                                             \
            __builtin_amdgcn_s_setprio(1);                                    \
            floatx4 qf = MFMA16(ah0, bfh[1][0], xw1);   /* f  */              \
            floatx4 qg = MFMA16(ah0, bfh[2][0], xw2);   /* g  */              \
            floatx4 qi = MFMA16(ah0, bfh[0][0], xw0);   /* i  */              \
            qf = MFMA16(ah1, bfh[1][1], qf);                                  \
            qg = MFMA16(ah1, bfh[2][1], qg);                                  \
            qi = MFMA16(ah1, bfh[0][1], qi);                                  \
            floatx4 qo = MFMA16(ah0, bfh[3][0], xw3);   /* o  */              \
            qf = MFMA16(ah2, bfh[1][2], qf);                                  \
            qg = MFMA16(ah2, bfh[2][2], qg);                                  \
            qi = MFMA16(ah2, bfh[0][2], qi);                                  \
            qo = MFMA16(ah1, bfh[3][1], qo);                                  \
            qf = MFMA16(ah3, bfh[1][3], qf);                                  \
            qg = MFMA16(ah3, bfh[2][3], qg);                                  \
            qi = MFMA16(ah3, bfh[0][3], qi);                                  \
            qo = MFMA16(ah2, bfh[3][2], qo);                                  \
            const float fg = fast_rcp(1.0f + exp2_(qf[R]));                   \
            const float eg = exp2_(qg[R]);                                    \
            const float fc = fg * c;                                          \
            const float gv = (1.0f - eg) * fast_rcp(1.0f + eg);               \
            const float ig = fast_rcp(1.0f + exp2_(qi[R]));                   \
            c = fmaf(ig, gv, fc);                                             \
            const float ec = exp2_(-2.8853900817779268f * c);                 \
            const float tc = (1.0f - ec) * fast_rcp(1.0f + ec);               \
            qo = MFMA16(ah3, bfh[3][3], qo);                                  \
            __builtin_amdgcn_s_setprio(0);                                    \
            const float og = fast_rcp(1.0f + exp2_(qo[R]));                   \
            const float h  = og * tc;                                         \
            if (kg == (P)) {                                                  \
                hb[(CUR) ^ 1][16 * w + col] = (_Float16)h;                    \
                *opr = h;                                                     \
            }                                                                 \
            opr += Hh;                                                        \
            asm volatile("s_waitcnt lgkmcnt(0)\n\ts_barrier" ::: "memory");   \
        }

        // phase P handles steps 4P..4P+3; c lineage hops lane-groups:
        // rotate c from group P-1 (or prev chunk's group 3) into group P.
        // Rotation rides the R==0 XTRA slot (after the ds_read issues; DS
        // returns are in-order per wave, so shfl-first would delay ah0).
#define PHASE(P, X0, X1, X2, X3)                                              \
        STEP(P, 0, 0, X0) STEP(P, 1, 1, X1) STEP(P, 2, 0, X2) STEP(P, 3, 1, X3)

        PHASE(0,
              (c = __shfl(c, (l + 48) & 63), nax0 = cvt8(xf0, xf1)),
              nax1 = cvt8(xf2, xf3),
              nxw0 = MFMA16(nax0, bfx[0][0], splat4(bs[0])),
              nxw1 = MFMA16(nax0, bfx[1][0], splat4(bs[1])))
        PHASE(1,
              (c = __shfl(c, (l + 48) & 63), nxw2 = MFMA16(nax0, bfx[2][0], splat4(bs[2]))),
              nxw3 = MFMA16(nax0, bfx[3][0], splat4(bs[3])),
              nxw0 = MFMA16(nax1, bfx[0][1], nxw0),
              nxw1 = MFMA16(nax1, bfx[1][1], nxw1))
        PHASE(2,
              (c = __shfl(c, (l + 48) & 63), nxw2 = MFMA16(nax1, bfx[2][1], nxw2)),
              nxw3 = MFMA16(nax1, bfx[3][1], nxw3),
              xf0 = *(const float4*)(xb2),
              xf1 = *(const float4*)(xb2 + 4))
        PHASE(3,
              (c = __shfl(c, (l + 48) & 63), xf2 = *(const float4*)(xb2 + 32)),
              xf3 = *(const float4*)(xb2 + 36),
              (void)0,
              (void)0)
#undef PHASE
#undef STEP

        xw0 = nxw0; xw1 = nxw1; xw2 = nxw2; xw3 = nxw3;
    }
}

extern "C" void kernel_launch(void* const* d_in, const int* in_sizes, int n_in,
                              void* d_out, int out_size, void* d_ws, size_t ws_size,
                              hipStream_t stream) {
    const float* data = (const float*)d_in[0];
    const float* W_ih = (const float*)d_in[1];
    const float* W_hh = (const float*)d_in[2];
    const float* b_ih = (const float*)d_in[3];
    const float* b_hh = (const float*)d_in[4];
    float* out = (float*)d_out;

    hipLaunchKernelGGL(lstm_mfma6, dim3(256), dim3(512), 0, stream,
                       data, W_ih, W_hh, b_ih, b_hh, out);
}